// Round 14
// baseline (154.873 us; speedup 1.0000x reference)
//
#include <hip/hip_runtime.h>

// GConvGRU with H=0: only two ChebConvs on X survive.
//   Z  = sigmoid(X@Wz0 + Tx1@Wz1 + Tx2@Wz2 + b_xz + b_hz)
//   Ht = tanh   (X@Wh0 + Tx1@Wh1 + Tx2@Wh2 + b_xh + b_hh)
//   H_new = (1-Z)*Ht
// R14 = R13 + k_gru single-phase staging at 64-tile: all 12 float4 loads
// issued up front, ONE barrier, then 432 MFMA uninterrupted (was 3 serial
// load->sync->compute phases = 3 latency exposures + 6 barriers).

#define N_NODES 50000
#define E_EDGES 800000
#define NC 64
#define BSH 6
#define BUKN 64
#define NBUK 782              // ceil(50000/64)
#define EPB 2048
#define NBLK 391              // ceil(800000/2048)
#define SLOT 16               // records per (bucket,block) cell
#define CVCAP 2048            // cv slots per bucket (mean 1023, 32 sigma)
#define OVFCAP 1024
#define RECL_CAP 1792         // LDS record stage per bucket (mean 1023, 24 sigma)

// ws element offsets (4B units), all distinct (no aliasing)
#define OFF_CV       0          // ll[782*2048]
#define OFF_ROWSTART 3203072    // int[50048]
#define OFF_ROWCNT   3253120    // int[50048]
#define OFF_DINV     3303168    // int[50048]
#define OFF_CNTDC    3353216    // int[782*391]
#define OFF_CNTSC    3658978    // int[782*391]
#define OFF_OVFN     3964740    // int[2]
#define OFF_OVFD     3964752    // int4[1024]
#define OFF_OVFS     3968848    // int4[1024]
#define OFF_WB       3972944    // short[49152]
#define OFF_TX1      3997520    // float[3200000]
#define OFF_TX2      7197520    // float[3200000]
#define OFF_SLOTD    10397520   // ll[782*391*16]
#define OFF_SLOTS    20181904   // ll[782*391*16] (ends 29966288)

typedef __attribute__((ext_vector_type(8))) short bf16x8;
typedef __attribute__((ext_vector_type(4))) float f32x4;

__device__ __forceinline__ unsigned bf16rne(float x) {
    unsigned u = __float_as_uint(x);
    return (u + 0x7fffu + ((u >> 16) & 1u)) >> 16;
}

// Single-pass scatter into fixed cells; extra 6 blocks build weight planes.
__global__ __launch_bounds__(256) void k_scatter(const int* __restrict__ ei,
        const float* __restrict__ ew,
        long long* __restrict__ slotD, long long* __restrict__ slotS,
        int* __restrict__ cntDC, int* __restrict__ cntSC,
        int* __restrict__ ovfn, int4* __restrict__ ovfD, int4* __restrict__ ovfS,
        const float* __restrict__ Wz, const float* __restrict__ Wh,
        short* __restrict__ WB) {
    int t = threadIdx.x, blk = blockIdx.x;
    if (blk >= NBLK) {                  // prepw part
        int mg = blk - NBLK;
        int m = mg >> 1, g = mg & 1;
        const float* W = (g ? Wh : Wz) + m * 4096;
        #pragma unroll
        for (int r = 0; r < 16; ++r) {
            int idx = r * 256 + t;      // c*64 + o
            int c = idx >> 6, o = idx & 63;
            float x = W[idx];
            unsigned hi = bf16rne(x);
            float fhi = __uint_as_float(hi << 16);
            unsigned lo = bf16rne(x - fhi);
            WB[(mg * 2 + 0) * 4096 + o * 64 + c] = (short)hi;
            WB[(mg * 2 + 1) * 4096 + o * 64 + c] = (short)lo;
        }
        return;
    }
    __shared__ int curD[NBUK], curS[NBUK];
    for (int b = t; b < NBUK; b += 256) { curD[b] = 0; curS[b] = 0; }
    __syncthreads();
    int e0 = blk * EPB;
    #pragma unroll
    for (int i = 0; i < 4; ++i) {
        int e = e0 + (i * 256 + t) * 2;
        if (e < E_EDGES) {
            int2 s2 = *(const int2*)&ei[e];
            int2 d2 = *(const int2*)&ei[E_EDGES + e];
            float2 w2 = *(const float2*)&ew[e];
            #pragma unroll
            for (int u = 0; u < 2; ++u) {
                int sN = u ? s2.y : s2.x;
                int dN = u ? d2.y : d2.x;
                float w = u ? w2.y : w2.x;
                long long wb = (long long)(unsigned)__float_as_uint(w) << 32;
                int bd = dN >> BSH;
                int pD = atomicAdd(&curD[bd], 1);
                if (pD < SLOT)
                    slotD[(size_t)(bd * NBLK + blk) * SLOT + pD] =
                        wb | (unsigned)((sN << BSH) | (dN & (BUKN - 1)));
                else {
                    int g = atomicAdd(&ovfn[0], 1);
                    if (g < OVFCAP) ovfD[g] = make_int4(sN, dN, __float_as_int(w), 0);
                }
                int bs = sN >> BSH;
                int pS = atomicAdd(&curS[bs], 1);
                if (pS < SLOT)
                    slotS[(size_t)(bs * NBLK + blk) * SLOT + pS] =
                        wb | (unsigned)(sN & (BUKN - 1));
                else {
                    int g = atomicAdd(&ovfn[1], 1);
                    if (g < OVFCAP) ovfS[g] = make_int4(sN, 0, __float_as_int(w), 0);
                }
            }
        }
    }
    __syncthreads();
    for (int b = t; b < NBUK; b += 256) {
        cntDC[b * NBLK + blk] = min(curD[b], SLOT);
        cntSC[b * NBLK + blk] = min(curS[b], SLOT);
    }
}

// Per-src-bucket degree from cells -> dinv.
__global__ __launch_bounds__(256) void k_deg(const long long* __restrict__ slotS,
        const int* __restrict__ cntSC, const int* __restrict__ ovfn,
        const int4* __restrict__ ovfS, float* __restrict__ dinv) {
    __shared__ float degL[BUKN];
    int t = threadIdx.x, b = blockIdx.x;
    if (t < BUKN) degL[t] = 0.f;
    __syncthreads();
    for (int c = t; c < NBLK; c += 256) {
        int n = cntSC[b * NBLK + c];
        size_t base = (size_t)(b * NBLK + c) * SLOT;
        for (int k = 0; k < n; ++k) {
            long long r = slotS[base + k];
            atomicAdd(&degL[(int)(r & (BUKN - 1))],
                      __uint_as_float((unsigned)(r >> 32)));
        }
    }
    int nov = min(ovfn[1], OVFCAP);
    for (int i = t; i < nov; i += 256) {
        int4 o = ovfS[i];
        if ((o.x >> BSH) == b)
            atomicAdd(&degL[o.x & (BUKN - 1)], __int_as_float(o.z));
    }
    __syncthreads();
    if (t < BUKN) {
        int node = b * BUKN + t;
        if (node < N_NODES) {
            float dg = degL[t];
            dinv[node] = dg > 0.f ? rsqrtf(dg) : 0.f;
        }
    }
}

// Cells -> exact CSR in bucket-padded cv (base b*CVCAP), val folded.
__global__ __launch_bounds__(256) void k_csr(const long long* __restrict__ slotD,
        const int* __restrict__ cntDC, const int* __restrict__ ovfn,
        const int4* __restrict__ ovfD, const float* __restrict__ dinv,
        long long* __restrict__ cv, int* __restrict__ row_start,
        int* __restrict__ row_cnt) {
    __shared__ long long recL[RECL_CAP];
    __shared__ int cnt[BUKN], cur[BUKN], nrec;
    __shared__ float dL[BUKN];
    int t = threadIdx.x, b = blockIdx.x;
    if (t < BUKN) {
        cnt[t] = 0;
        int node = b * BUKN + t;
        dL[t] = (node < N_NODES) ? dinv[node] : 0.f;
    }
    if (t == 0) nrec = 0;
    __syncthreads();
    for (int c = t; c < NBLK; c += 256) {
        int n = cntDC[b * NBLK + c];
        size_t base = (size_t)(b * NBLK + c) * SLOT;
        for (int k = 0; k < n; ++k) {
            long long r = slotD[base + k];
            int idx = atomicAdd(&nrec, 1);
            if (idx < RECL_CAP) recL[idx] = r;
            atomicAdd(&cnt[(int)(r & (BUKN - 1))], 1);
        }
    }
    int nov = min(ovfn[0], OVFCAP);
    for (int i = t; i < nov; i += 256) {
        int4 o = ovfD[i];
        if ((o.y >> BSH) == b) {
            long long r = ((long long)(unsigned)o.z << 32) |
                          (unsigned)((o.x << BSH) | (o.y & (BUKN - 1)));
            int idx = atomicAdd(&nrec, 1);
            if (idx < RECL_CAP) recL[idx] = r;
            atomicAdd(&cnt[o.y & (BUKN - 1)], 1);
        }
    }
    __syncthreads();
    if (t < BUKN) {
        int x = cnt[t];
        int orig = x;
        #pragma unroll
        for (int off = 1; off < BUKN; off <<= 1) {
            int v = __shfl_up(x, off, 64);
            if ((t & 63) >= off) x += v;
        }
        cur[t] = x - orig;
        int node = b * BUKN + t;
        if (node < N_NODES) {
            row_start[node] = b * CVCAP + (x - orig);
            row_cnt[node] = orig;
        }
    }
    __syncthreads();
    int n = min(nrec, RECL_CAP);
    for (int i = t; i < n; i += 256) {
        long long r = recL[i];
        int m = (int)(r & 0xffffffffLL);
        float w = __uint_as_float((unsigned)(r >> 32));
        int rr = m & (BUKN - 1);
        int sN = m >> BSH;
        float val = -w * dinv[sN] * dL[rr];
        int pos = b * CVCAP + atomicAdd(&cur[rr], 1);
        cv[pos] = ((long long)__float_as_int(val) << 32) | (unsigned)sN;
    }
}

// SpMM: one wave per row; 16 lanes/edge x 4 edges/instr (R9-proven body).
template<int SCALE, int SUB>
__global__ __launch_bounds__(256) void k_spmm(
        const int* __restrict__ row_start, const int* __restrict__ row_cnt,
        const long long* __restrict__ cv, const float* __restrict__ xin,
        const float* __restrict__ xprev, float* __restrict__ out) {
    int wid = (blockIdx.x << 2) + (threadIdx.x >> 6);
    int l = threadIdx.x & 63;
    if (wid >= N_NODES) return;
    int start = row_start[wid];
    int end   = start + row_cnt[wid];
    int sub = l >> 4;
    int q   = l & 15;
    float4 acc = make_float4(0.f, 0.f, 0.f, 0.f);
    for (int j = start; j < end; j += 8) {
        int jA = j + sub;
        int jB = j + 4 + sub;
        long long pA = (jA < end) ? cv[jA] : 0LL;
        long long pB = (jB < end) ? cv[jB] : 0LL;
        float4 xA = *(const float4*)&xin[(size_t)(unsigned)(pA & 0xffffffffLL) * NC + q * 4];
        float4 xB = *(const float4*)&xin[(size_t)(unsigned)(pB & 0xffffffffLL) * NC + q * 4];
        float vA = __int_as_float((int)(pA >> 32));
        float vB = __int_as_float((int)(pB >> 32));
        acc.x = fmaf(vA, xA.x, acc.x);
        acc.y = fmaf(vA, xA.y, acc.y);
        acc.z = fmaf(vA, xA.z, acc.z);
        acc.w = fmaf(vA, xA.w, acc.w);
        acc.x = fmaf(vB, xB.x, acc.x);
        acc.y = fmaf(vB, xB.y, acc.y);
        acc.z = fmaf(vB, xB.z, acc.z);
        acc.w = fmaf(vB, xB.w, acc.w);
    }
    #pragma unroll
    for (int m = 16; m <= 32; m <<= 1) {
        acc.x += __shfl_xor(acc.x, m, 64);
        acc.y += __shfl_xor(acc.y, m, 64);
        acc.z += __shfl_xor(acc.z, m, 64);
        acc.w += __shfl_xor(acc.w, m, 64);
    }
    if (sub == 0) {
        float4 r;
        r.x = (float)SCALE * acc.x;
        r.y = (float)SCALE * acc.y;
        r.z = (float)SCALE * acc.z;
        r.w = (float)SCALE * acc.w;
        if (SUB) {
            float4 xo = *(const float4*)&xprev[(size_t)wid * NC + q * 4];
            r.x -= xo.x; r.y -= xo.y; r.z -= xo.z; r.w -= xo.w;
        }
        *(float4*)&out[(size_t)wid * NC + q * 4] = r;
    }
}

// bf16x3 MFMA GRU, 64-node tile, SINGLE-PHASE staging: all 12 float4 loads
// issued up front, one barrier, 432 MFMA uninterrupted. 48KB LDS.
__global__ __launch_bounds__(256) void k_gru(
        const float* __restrict__ X, const float* __restrict__ Tx1,
        const float* __restrict__ Tx2, const short* __restrict__ WB,
        const float* __restrict__ bxz, const float* __restrict__ bhz,
        const float* __restrict__ bxh, const float* __restrict__ bhh,
        float* __restrict__ out) {
    __shared__ short Ahi[3 * 64 * 64];
    __shared__ short Alo[3 * 64 * 64];
    int tid = threadIdx.x;
    int l = tid & 63;
    int w = tid >> 6;
    int node0 = blockIdx.x * 64;

    const float* ins[3] = {X, Tx1, Tx2};

    // Issue all 12 global loads back-to-back (latency overlapped).
    float4 v[3][4];
    #pragma unroll
    for (int m = 0; m < 3; ++m) {
        const float* ip = ins[m];
        #pragma unroll
        for (int r = 0; r < 4; ++r) {
            int fidx = r * 256 + tid;        // 0..1023 float4 units
            int n = fidx >> 4, c4 = fidx & 15;
            int gn = node0 + n;
            v[m][r] = (gn < N_NODES) ? *(const float4*)&ip[(size_t)gn * 64 + c4 * 4]
                                     : make_float4(0.f, 0.f, 0.f, 0.f);
        }
    }
    // Convert + swizzled LDS write, then ONE barrier.
    #pragma unroll
    for (int m = 0; m < 3; ++m) {
        #pragma unroll
        for (int r = 0; r < 4; ++r) {
            int fidx = r * 256 + tid;
            int n = fidx >> 4, c4 = fidx & 15;
            float4 x = v[m][r];
            unsigned h0 = bf16rne(x.x), h1 = bf16rne(x.y),
                     h2 = bf16rne(x.z), h3 = bf16rne(x.w);
            unsigned q0 = bf16rne(x.x - __uint_as_float(h0 << 16));
            unsigned q1 = bf16rne(x.y - __uint_as_float(h1 << 16));
            unsigned q2 = bf16rne(x.z - __uint_as_float(h2 << 16));
            unsigned q3 = bf16rne(x.w - __uint_as_float(h3 << 16));
            int kk = (c4 * 4) ^ ((n & 7) << 3);    // XOR swizzle (bank fix)
            int base = m * 4096 + n * 64 + kk;
            *(uint2*)&Ahi[base] = make_uint2(h0 | (h1 << 16), h2 | (h3 << 16));
            *(uint2*)&Alo[base] = make_uint2(q0 | (q1 << 16), q2 | (q3 << 16));
        }
    }
    __syncthreads();

    f32x4 accz[4], acch[4];
    #pragma unroll
    for (int mt = 0; mt < 4; ++mt) {
        accz[mt] = (f32x4){0.f, 0.f, 0.f, 0.f};
        acch[mt] = (f32x4){0.f, 0.f, 0.f, 0.f};
    }
    int o = w * 16 + (l & 15);

    #pragma unroll
    for (int m = 0; m < 3; ++m) {
        const short* wbm = WB + m * 4 * 4096;
        #pragma unroll
        for (int kt = 0; kt < 2; ++kt) {
            int k0 = kt * 32 + (l >> 4) * 8;
            bf16x8 ah[4], al[4];
            #pragma unroll
            for (int mt = 0; mt < 4; ++mt) {
                int row = mt * 16 + (l & 15);
                int kk = k0 ^ ((row & 7) << 3);
                int base = m * 4096 + row * 64 + kk;
                ah[mt] = *(const bf16x8*)&Ahi[base];
                al[mt] = *(const bf16x8*)&Alo[base];
            }
            {
                bf16x8 bh_ = *(const bf16x8*)&wbm[0 * 4096 + o * 64 + k0];
                bf16x8 bl_ = *(const bf16x8*)&wbm[1 * 4096 + o * 64 + k0];
                #pragma unroll
                for (int mt = 0; mt < 4; ++mt) {
                    accz[mt] = __builtin_amdgcn_mfma_f32_16x16x32_bf16(ah[mt], bh_, accz[mt], 0, 0, 0);
                    accz[mt] = __builtin_amdgcn_mfma_f32_16x16x32_bf16(ah[mt], bl_, accz[mt], 0, 0, 0);
                    accz[mt] = __builtin_amdgcn_mfma_f32_16x16x32_bf16(al[mt], bh_, accz[mt], 0, 0, 0);
                }
            }
            {
                bf16x8 bh_ = *(const bf16x8*)&wbm[2 * 4096 + o * 64 + k0];
                bf16x8 bl_ = *(const bf16x8*)&wbm[3 * 4096 + o * 64 + k0];
                #pragma unroll
                for (int mt = 0; mt < 4; ++mt) {
                    acch[mt] = __builtin_amdgcn_mfma_f32_16x16x32_bf16(ah[mt], bh_, acch[mt], 0, 0, 0);
                    acch[mt] = __builtin_amdgcn_mfma_f32_16x16x32_bf16(ah[mt], bl_, acch[mt], 0, 0, 0);
                    acch[mt] = __builtin_amdgcn_mfma_f32_16x16x32_bf16(al[mt], bh_, acch[mt], 0, 0, 0);
                }
            }
        }
    }

    float bz = bxz[o] + bhz[o];
    float bh = bxh[o] + bhh[o];
    #pragma unroll
    for (int mt = 0; mt < 4; ++mt) {
        #pragma unroll
        for (int r = 0; r < 4; ++r) {
            int node = node0 + mt * 16 + (l >> 4) * 4 + r;
            if (node < N_NODES) {
                float z = accz[mt][r] + bz;
                float h = acch[mt][r] + bh;
                float sig = 1.f / (1.f + __expf(-z));
                float e2 = __expf(-2.f * h);
                float th = (1.f - e2) / (1.f + e2);
                out[(size_t)node * 64 + o] = (1.f - sig) * th;
            }
        }
    }
}

extern "C" void kernel_launch(void* const* d_in, const int* in_sizes, int n_in,
                              void* d_out, int out_size, void* d_ws, size_t ws_size,
                              hipStream_t stream) {
    const float* X   = (const float*)d_in[0];
    const int*   ei  = (const int*)d_in[1];
    const float* ew  = (const float*)d_in[2];
    const float* Wxz = (const float*)d_in[3];
    const float* Wxh = (const float*)d_in[7];
    const float* bxz = (const float*)d_in[9];
    const float* bhz = (const float*)d_in[10];
    const float* bxh = (const float*)d_in[13];
    const float* bhh = (const float*)d_in[14];
    float* out = (float*)d_out;

    int* ws_i = (int*)d_ws;
    float* ws_f = (float*)d_ws;

    long long* cv       = (long long*)(ws_i + OFF_CV);
    int*       rowstart = ws_i + OFF_ROWSTART;
    int*       rowcnt   = ws_i + OFF_ROWCNT;
    float*     dinv     = ws_f + OFF_DINV;
    int*       cntDC    = ws_i + OFF_CNTDC;
    int*       cntSC    = ws_i + OFF_CNTSC;
    int*       ovfn     = ws_i + OFF_OVFN;
    int4*      ovfD     = (int4*)(ws_i + OFF_OVFD);
    int4*      ovfS     = (int4*)(ws_i + OFF_OVFS);
    short*     WB       = (short*)(ws_i + OFF_WB);
    float*     tx1      = ws_f + OFF_TX1;
    float*     tx2      = ws_f + OFF_TX2;
    long long* slotD    = (long long*)(ws_i + OFF_SLOTD);
    long long* slotS    = (long long*)(ws_i + OFF_SLOTS);

    // zero the two overflow counters
    hipMemsetAsync((void*)ovfn, 0, 8, stream);

    const int TB = 256;
    k_scatter<<<NBLK + 6, TB, 0, stream>>>(ei, ew, slotD, slotS, cntDC, cntSC,
                                           ovfn, ovfD, ovfS, Wxz, Wxh, WB);
    k_deg<<<NBUK, TB, 0, stream>>>(slotS, cntSC, ovfn, ovfS, dinv);
    k_csr<<<NBUK, TB, 0, stream>>>(slotD, cntDC, ovfn, ovfD, dinv, cv,
                                   rowstart, rowcnt);

    // Tx1 = L_hat @ X
    k_spmm<1, 0><<<(N_NODES + 3) / 4, TB, 0, stream>>>(rowstart, rowcnt, cv, X, X, tx1);
    // Tx2 = 2 * L_hat @ Tx1 - X
    k_spmm<2, 1><<<(N_NODES + 3) / 4, TB, 0, stream>>>(rowstart, rowcnt, cv, tx1, X, tx2);

    k_gru<<<NBUK, TB, 0, stream>>>(X, tx1, tx2, WB, bxz, bhz, bxh, bhh, out);
}

// Round 15
// 150.200 us; speedup vs baseline: 1.0311x; 1.0311x over previous
//
#include <hip/hip_runtime.h>

// GConvGRU with H=0: only two ChebConvs on X survive.
//   Z  = sigmoid(X@Wz0 + Tx1@Wz1 + Tx2@Wz2 + b_xz + b_hz)
//   Ht = tanh   (X@Wh0 + Tx1@Wh1 + Tx2@Wh2 + b_xh + b_hh)
//   H_new = (1-Z)*Ht
// R15 = R9 (proven 147us: counting-sort build + float4-gather spmm)
// + k_gru staged via async global_load_lds (fp32 planes in LDS, zero VGPR
// staging cost, 12KB in flight/wave), bf16 hi/lo conversion on the fly at
// fragment read. Linear LDS dest + pre-swizzled global source (rule #21).

#define N_NODES 50000
#define E_EDGES 800000
#define NC 64
#define BSH 6                 // 64 nodes per bucket
#define BUKN 64
#define NBUK 782              // ceil(50000/64)
#define EPB 2048              // edges per hist/scatter block
#define NBLK 391              // ceil(800000/2048)

// ws element offsets (4B units); aliases are dead before their host buffer is written
#define OFF_CV       0          // long long[800000] (exact CSR: val|src)
#define OFF_ROWSTART 1600000    // int[50001] (pad 50016)
#define OFF_TOTD     1650016    // int[784]
#define OFF_BASED    1650800    // int[784]
#define OFF_TOTS     1651584    // int[784]
#define OFF_BASES    1652368    // int[784]
#define OFF_TX1      1653152    // float[3200000]
#define OFF_RECD     1653152    //   alias: long long[800000], dead after k_csr
#define OFF_DINV     3253152    //   alias: float[50016], dead after k_csr
#define OFF_CNTD     3303168    //   alias: int[782*391], dead after k_scatter
#define OFF_TX2      4853152    // float[3200000] (ends 8053152)
#define OFF_RECS     4853152    //   alias: long long[800000], dead after k_deg
#define OFF_CNTS     6453152    //   alias: int[782*391], dead after k_scatter
#define OFF_WB       8053152    // short[49152] bf16 weight planes (past TX2)

typedef __attribute__((ext_vector_type(8))) short bf16x8;
typedef __attribute__((ext_vector_type(4))) float f32x4;

__device__ __forceinline__ unsigned bf16rne(float x) {
    unsigned u = __float_as_uint(x);
    return (u + 0x7fffu + ((u >> 16) & 1u)) >> 16;
}

// hist blocks bin edges; extra 6 blocks build bf16 weight planes (prepw).
__global__ __launch_bounds__(256) void k_hist(const int* __restrict__ ei,
        int* __restrict__ cntD, int* __restrict__ cntS,
        const float* __restrict__ Wz, const float* __restrict__ Wh,
        short* __restrict__ WB) {
    int t = threadIdx.x, blk = blockIdx.x;
    if (blk >= NBLK) {                  // prepw part
        int mg = blk - NBLK;            // 0..5 = (m,g)
        int m = mg >> 1, g = mg & 1;
        const float* W = (g ? Wh : Wz) + m * 4096;
        #pragma unroll
        for (int r = 0; r < 16; ++r) {
            int idx = r * 256 + t;      // c*64 + o
            int c = idx >> 6, o = idx & 63;
            float x = W[idx];
            unsigned hi = bf16rne(x);
            float fhi = __uint_as_float(hi << 16);
            unsigned lo = bf16rne(x - fhi);
            WB[(mg * 2 + 0) * 4096 + o * 64 + c] = (short)hi;
            WB[(mg * 2 + 1) * 4096 + o * 64 + c] = (short)lo;
        }
        return;
    }
    __shared__ int hD[NBUK], hS[NBUK];
    for (int b = t; b < NBUK; b += 256) { hD[b] = 0; hS[b] = 0; }
    __syncthreads();
    int e0 = blk * EPB;
    #pragma unroll
    for (int i = 0; i < 8; ++i) {
        int e = e0 + i * 256 + t;
        if (e < E_EDGES) {
            atomicAdd(&hS[ei[e] >> BSH], 1);
            atomicAdd(&hD[ei[E_EDGES + e] >> BSH], 1);
        }
    }
    __syncthreads();
    for (int b = t; b < NBUK; b += 256) {
        cntD[b * NBLK + blk] = hD[b];
        cntS[b * NBLK + blk] = hS[b];
    }
}

__global__ __launch_bounds__(256) void k_scanPB(int* __restrict__ cntD,
        int* __restrict__ cntS, int* __restrict__ totD, int* __restrict__ totS) {
    __shared__ int s[512];
    int t = threadIdx.x;
    int row = blockIdx.x; int* cnt; int* tot;
    if (row < NBUK) { cnt = cntD; tot = totD; }
    else            { row -= NBUK; cnt = cntS; tot = totS; }
    int v0 = (t < NBLK) ? cnt[row * NBLK + t] : 0;
    int v1 = (256 + t < NBLK) ? cnt[row * NBLK + 256 + t] : 0;
    s[t] = v0; s[256 + t] = v1;
    __syncthreads();
    for (int off = 1; off < 512; off <<= 1) {
        int a = (t >= off) ? s[t - off] : 0;
        int b = (256 + t >= off) ? s[256 + t - off] : 0;
        __syncthreads();
        s[t] += a; s[256 + t] += b;
        __syncthreads();
    }
    if (t < NBLK) cnt[row * NBLK + t] = s[t] - v0;
    if (256 + t < NBLK) cnt[row * NBLK + 256 + t] = s[256 + t] - v1;
    if (t == 0) tot[row] = s[511];
}

__global__ __launch_bounds__(256) void k_scanTot(int* __restrict__ totD,
        int* __restrict__ baseD, int* __restrict__ totS, int* __restrict__ baseS) {
    __shared__ int s[1024];
    int t = threadIdx.x;
    int* tot  = blockIdx.x ? totS  : totD;
    int* base = blockIdx.x ? baseS : baseD;
    int v[4];
    #pragma unroll
    for (int q = 0; q < 4; ++q) {
        int i = q * 256 + t;
        v[q] = (i < NBUK) ? tot[i] : 0;
        s[i] = v[q];
    }
    __syncthreads();
    for (int off = 1; off < 1024; off <<= 1) {
        int a[4];
        #pragma unroll
        for (int q = 0; q < 4; ++q) {
            int i = q * 256 + t;
            a[q] = (i >= off) ? s[i - off] : 0;
        }
        __syncthreads();
        #pragma unroll
        for (int q = 0; q < 4; ++q) s[q * 256 + t] += a[q];
        __syncthreads();
    }
    #pragma unroll
    for (int q = 0; q < 4; ++q) {
        int i = q * 256 + t;
        if (i < NBUK) base[i] = s[i] - v[q];
    }
}

__global__ __launch_bounds__(256) void k_scatter(const int* __restrict__ ei,
        const float* __restrict__ ew, const int* __restrict__ offD,
        const int* __restrict__ offS, const int* __restrict__ baseD,
        const int* __restrict__ baseS, long long* __restrict__ recD,
        long long* __restrict__ recS) {
    __shared__ int curD[NBUK], curS[NBUK];
    int t = threadIdx.x, blk = blockIdx.x;
    for (int b = t; b < NBUK; b += 256) {
        curD[b] = baseD[b] + offD[b * NBLK + blk];
        curS[b] = baseS[b] + offS[b * NBLK + blk];
    }
    __syncthreads();
    int e0 = blk * EPB;
    #pragma unroll
    for (int i = 0; i < 8; ++i) {
        int e = e0 + i * 256 + t;
        if (e < E_EDGES) {
            int sN = ei[e], dN = ei[E_EDGES + e];
            long long wb = (long long)(unsigned)__float_as_uint(ew[e]) << 32;
            int pD = atomicAdd(&curD[dN >> BSH], 1);
            recD[pD] = wb | (unsigned)((sN << BSH) | (dN & (BUKN - 1)));
            int pS = atomicAdd(&curS[sN >> BSH], 1);
            recS[pS] = wb | (unsigned)(sN & (BUKN - 1));
        }
    }
}

__global__ __launch_bounds__(256) void k_deg(const long long* __restrict__ recS,
        const int* __restrict__ totS, const int* __restrict__ baseS,
        float* __restrict__ dinv) {
    __shared__ float degL[BUKN];
    int t = threadIdx.x, b = blockIdx.x;
    if (t < BUKN) degL[t] = 0.f;
    __syncthreads();
    int st = baseS[b], n = totS[b];
    for (int i = t; i < n; i += 256) {
        long long r = recS[st + i];
        atomicAdd(&degL[(int)(r & (BUKN - 1))], __uint_as_float((unsigned)(r >> 32)));
    }
    __syncthreads();
    if (t < BUKN) {
        int node = b * BUKN + t;
        if (node < N_NODES) {
            float dg = degL[t];
            dinv[node] = dg > 0.f ? rsqrtf(dg) : 0.f;
        }
    }
}

__global__ __launch_bounds__(256) void k_csr(const long long* __restrict__ recD,
        const int* __restrict__ totD, const int* __restrict__ baseD,
        const float* __restrict__ dinv, long long* __restrict__ cv,
        int* __restrict__ row_start) {
    __shared__ int cnt[BUKN], cur[BUKN];
    __shared__ float dL[BUKN];
    int t = threadIdx.x, b = blockIdx.x;
    if (t < BUKN) {
        cnt[t] = 0;
        int node = b * BUKN + t;
        dL[t] = (node < N_NODES) ? dinv[node] : 0.f;
    }
    __syncthreads();
    int st = baseD[b], n = totD[b];
    for (int i = t; i < n; i += 256)
        atomicAdd(&cnt[(int)(recD[st + i] & (BUKN - 1))], 1);
    __syncthreads();
    if (t < BUKN) {
        int x = cnt[t];
        int orig = x;
        #pragma unroll
        for (int off = 1; off < BUKN; off <<= 1) {
            int v = __shfl_up(x, off, 64);
            if ((t & 63) >= off) x += v;
        }
        cur[t] = x - orig;
        int node = b * BUKN + t;
        if (node < N_NODES) row_start[node] = st + (x - orig);
    }
    if (b == 0 && t == 0) row_start[N_NODES] = E_EDGES;
    __syncthreads();
    for (int i = t; i < n; i += 256) {
        long long r = recD[st + i];
        int m = (int)(r & 0xffffffffLL);
        float w = __uint_as_float((unsigned)(r >> 32));
        int rr = m & (BUKN - 1);
        int sN = m >> BSH;
        float val = -w * dinv[sN] * dL[rr];
        int pos = st + atomicAdd(&cur[rr], 1);
        cv[pos] = ((long long)__float_as_int(val) << 32) | (unsigned)sN;
    }
}

// SpMM: one wave per row; 16 lanes per edge, 4 edges per gather instruction.
// Byte-exact R9 body.
template<int SCALE, int SUB>
__global__ __launch_bounds__(256) void k_spmm(
        const int* __restrict__ row_start, const long long* __restrict__ cv,
        const float* __restrict__ xin, const float* __restrict__ xprev,
        float* __restrict__ out) {
    int wid = (blockIdx.x << 2) + (threadIdx.x >> 6);
    int l = threadIdx.x & 63;
    if (wid >= N_NODES) return;
    int start = row_start[wid];
    int end   = row_start[wid + 1];
    int sub = l >> 4;        // edge slot in group
    int q   = l & 15;        // channel quad
    float4 acc = make_float4(0.f, 0.f, 0.f, 0.f);
    for (int j = start; j < end; j += 8) {
        int jA = j + sub;
        int jB = j + 4 + sub;
        long long pA = (jA < end) ? cv[jA] : 0LL;
        long long pB = (jB < end) ? cv[jB] : 0LL;
        float4 xA = *(const float4*)&xin[(size_t)(unsigned)(pA & 0xffffffffLL) * NC + q * 4];
        float4 xB = *(const float4*)&xin[(size_t)(unsigned)(pB & 0xffffffffLL) * NC + q * 4];
        float vA = __int_as_float((int)(pA >> 32));
        float vB = __int_as_float((int)(pB >> 32));
        acc.x = fmaf(vA, xA.x, acc.x);
        acc.y = fmaf(vA, xA.y, acc.y);
        acc.z = fmaf(vA, xA.z, acc.z);
        acc.w = fmaf(vA, xA.w, acc.w);
        acc.x = fmaf(vB, xB.x, acc.x);
        acc.y = fmaf(vB, xB.y, acc.y);
        acc.z = fmaf(vB, xB.z, acc.z);
        acc.w = fmaf(vB, xB.w, acc.w);
    }
    #pragma unroll
    for (int m = 16; m <= 32; m <<= 1) {
        acc.x += __shfl_xor(acc.x, m, 64);
        acc.y += __shfl_xor(acc.y, m, 64);
        acc.z += __shfl_xor(acc.z, m, 64);
        acc.w += __shfl_xor(acc.w, m, 64);
    }
    if (sub == 0) {
        float4 r;
        r.x = (float)SCALE * acc.x;
        r.y = (float)SCALE * acc.y;
        r.z = (float)SCALE * acc.z;
        r.w = (float)SCALE * acc.w;
        if (SUB) {
            float4 xo = *(const float4*)&xprev[(size_t)wid * NC + q * 4];
            r.x -= xo.x; r.y -= xo.y; r.z -= xo.z; r.w -= xo.w;
        }
        *(float4*)&out[(size_t)wid * NC + q * 4] = r;
    }
}

// bf16x3 MFMA GRU, 64-node tile, async global_load_lds staging of fp32
// planes (12 x 1KB DMA per wave, zero VGPR staging), bf16 hi/lo conversion
// at fragment read. Linear LDS dest + pre-swizzled global source: LDS
// 16B-granule (n,g) holds global granule g ^ ((n&7)<<1); fragment read at
// granule (k0>>2)^((row&7)<<1) recovers contiguous k0..k0+7 (swz even, so
// granule pairs stay adjacent). 48KB LDS, 3 blocks/CU (same as R9).
__global__ __launch_bounds__(256) void k_gru(
        const float* __restrict__ X, const float* __restrict__ Tx1,
        const float* __restrict__ Tx2, const short* __restrict__ WB,
        const float* __restrict__ bxz, const float* __restrict__ bhz,
        const float* __restrict__ bxh, const float* __restrict__ bhh,
        float* __restrict__ out) {
    __shared__ float Alds[3 * 64 * 64];
    int tid = threadIdx.x;
    int l = tid & 63;
    int w = tid >> 6;
    int node0 = blockIdx.x * 64;

    const float* ins[3] = {X, Tx1, Tx2};

    // Async staging: per matrix, wave w covers granules [w*256, w*256+256)
    // in 4 calls of 64 granules (1KB each). dst is wave-uniform; lane offset
    // is implicit (lane*16B). Source address carries the granule swizzle.
    #pragma unroll
    for (int m = 0; m < 3; ++m) {
        const float* ip = ins[m];
        #pragma unroll
        for (int it = 0; it < 4; ++it) {
            int lg = w * 256 + it * 64 + l;      // granule in [0,1024)
            int n = lg >> 4, g = lg & 15;
            int gs = g ^ ((n & 7) << 1);         // pre-swizzled source granule
            int gn = node0 + n;
            const float* src = ip + (size_t)gn * 64 + gs * 4;
            float* dst = &Alds[m * 4096 + w * 1024 + it * 256];
            if (gn < N_NODES)
                __builtin_amdgcn_global_load_lds(
                    (const __attribute__((address_space(1))) void*)src,
                    (__attribute__((address_space(3))) void*)dst, 16, 0, 0);
        }
    }
    __syncthreads();

    f32x4 accz[4], acch[4];
    #pragma unroll
    for (int mt = 0; mt < 4; ++mt) {
        accz[mt] = (f32x4){0.f, 0.f, 0.f, 0.f};
        acch[mt] = (f32x4){0.f, 0.f, 0.f, 0.f};
    }
    int o = w * 16 + (l & 15);

    #pragma unroll
    for (int m = 0; m < 3; ++m) {
        const short* wbm = WB + m * 4 * 4096;
        #pragma unroll
        for (int kt = 0; kt < 2; ++kt) {
            int k0 = kt * 32 + (l >> 4) * 8;
            bf16x8 ah[4], al[4];
            #pragma unroll
            for (int mt = 0; mt < 4; ++mt) {
                int row = mt * 16 + (l & 15);
                int g0 = (k0 >> 2) ^ ((row & 7) << 1);   // even; pair adjacent
                const float* p = &Alds[m * 4096 + row * 64 + g0 * 4];
                float4 fa = *(const float4*)p;
                float4 fb = *(const float4*)(p + 4);
                float f0[8] = {fa.x, fa.y, fa.z, fa.w, fb.x, fb.y, fb.z, fb.w};
                #pragma unroll
                for (int e = 0; e < 8; ++e) {
                    unsigned hi = bf16rne(f0[e]);
                    ah[mt][e] = (short)hi;
                    al[mt][e] = (short)bf16rne(f0[e] - __uint_as_float(hi << 16));
                }
            }
            {
                bf16x8 bh_ = *(const bf16x8*)&wbm[0 * 4096 + o * 64 + k0];
                bf16x8 bl_ = *(const bf16x8*)&wbm[1 * 4096 + o * 64 + k0];
                #pragma unroll
                for (int mt = 0; mt < 4; ++mt) {
                    accz[mt] = __builtin_amdgcn_mfma_f32_16x16x32_bf16(ah[mt], bh_, accz[mt], 0, 0, 0);
                    accz[mt] = __builtin_amdgcn_mfma_f32_16x16x32_bf16(ah[mt], bl_, accz[mt], 0, 0, 0);
                    accz[mt] = __builtin_amdgcn_mfma_f32_16x16x32_bf16(al[mt], bh_, accz[mt], 0, 0, 0);
                }
            }
            {
                bf16x8 bh_ = *(const bf16x8*)&wbm[2 * 4096 + o * 64 + k0];
                bf16x8 bl_ = *(const bf16x8*)&wbm[3 * 4096 + o * 64 + k0];
                #pragma unroll
                for (int mt = 0; mt < 4; ++mt) {
                    acch[mt] = __builtin_amdgcn_mfma_f32_16x16x32_bf16(ah[mt], bh_, acch[mt], 0, 0, 0);
                    acch[mt] = __builtin_amdgcn_mfma_f32_16x16x32_bf16(ah[mt], bl_, acch[mt], 0, 0, 0);
                    acch[mt] = __builtin_amdgcn_mfma_f32_16x16x32_bf16(al[mt], bh_, acch[mt], 0, 0, 0);
                }
            }
        }
    }

    // epilogue: C/D layout col=lane&15 (o), row=(lane>>4)*4+r (node)
    float bz = bxz[o] + bhz[o];
    float bh = bxh[o] + bhh[o];
    #pragma unroll
    for (int mt = 0; mt < 4; ++mt) {
        #pragma unroll
        for (int r = 0; r < 4; ++r) {
            int node = node0 + mt * 16 + (l >> 4) * 4 + r;
            if (node < N_NODES) {
                float z = accz[mt][r] + bz;
                float h = acch[mt][r] + bh;
                float sig = 1.f / (1.f + __expf(-z));
                float e2 = __expf(-2.f * h);
                float th = (1.f - e2) / (1.f + e2);
                out[(size_t)node * 64 + o] = (1.f - sig) * th;
            }
        }
    }
}

extern "C" void kernel_launch(void* const* d_in, const int* in_sizes, int n_in,
                              void* d_out, int out_size, void* d_ws, size_t ws_size,
                              hipStream_t stream) {
    const float* X   = (const float*)d_in[0];
    const int*   ei  = (const int*)d_in[1];
    const float* ew  = (const float*)d_in[2];
    const float* Wxz = (const float*)d_in[3];
    const float* Wxh = (const float*)d_in[7];
    const float* bxz = (const float*)d_in[9];
    const float* bhz = (const float*)d_in[10];
    const float* bxh = (const float*)d_in[13];
    const float* bhh = (const float*)d_in[14];
    float* out = (float*)d_out;

    float* ws_f = (float*)d_ws;
    int*   ws_i = (int*)d_ws;

    long long* cv       = (long long*)(ws_i + OFF_CV);
    int*       rowstart = ws_i + OFF_ROWSTART;
    int*       totD     = ws_i + OFF_TOTD;
    int*       baseD    = ws_i + OFF_BASED;
    int*       totS     = ws_i + OFF_TOTS;
    int*       baseS    = ws_i + OFF_BASES;
    float*     tx1      = ws_f + OFF_TX1;
    long long* recD     = (long long*)(ws_i + OFF_RECD);
    float*     dinv     = ws_f + OFF_DINV;
    int*       cntD     = ws_i + OFF_CNTD;
    float*     tx2      = ws_f + OFF_TX2;
    long long* recS     = (long long*)(ws_i + OFF_RECS);
    int*       cntS     = ws_i + OFF_CNTS;
    short*     WB       = (short*)(ws_i + OFF_WB);

    const int TB = 256;
    k_hist<<<NBLK + 6, TB, 0, stream>>>(ei, cntD, cntS, Wxz, Wxh, WB);
    k_scanPB<<<2 * NBUK, TB, 0, stream>>>(cntD, cntS, totD, totS);
    k_scanTot<<<2, TB, 0, stream>>>(totD, baseD, totS, baseS);
    k_scatter<<<NBLK, TB, 0, stream>>>(ei, ew, cntD, cntS, baseD, baseS, recD, recS);
    k_deg<<<NBUK, TB, 0, stream>>>(recS, totS, baseS, dinv);
    k_csr<<<NBUK, TB, 0, stream>>>(recD, totD, baseD, dinv, cv, rowstart);

    // Tx1 = L_hat @ X
    k_spmm<1, 0><<<(N_NODES + 3) / 4, TB, 0, stream>>>(rowstart, cv, X, X, tx1);
    // Tx2 = 2 * L_hat @ Tx1 - X
    k_spmm<2, 1><<<(N_NODES + 3) / 4, TB, 0, stream>>>(rowstart, cv, tx1, X, tx2);

    k_gru<<<NBUK, TB, 0, stream>>>(X, tx1, tx2, WB, bxz, bhz, bxh, bhh, out);
}